// Round 3
// baseline (1933.032 us; speedup 1.0000x reference)
//
#include <hip/hip_runtime.h>
#include <math.h>

#define NV 50000
#define NR 500
#define EVV 400000
#define EVI 100000
#define EIV 100000

// ---------------- CSR build (batched over all 3 topologies) ----------------
// cnt_all layout: [vv: NV][vi: NR][iv: NV]
// rp_all  layout: [vv: NV+1][vi: NR+1][iv: NV+1]
// src_all layout: [vv: EVV][vi: EVI][iv: EIV]
__global__ void hist_all_kernel(const int* __restrict__ vv_s, const int* __restrict__ vv_d,
                                const int* __restrict__ vi_d, const int* __restrict__ iv_d,
                                unsigned* __restrict__ cnt_all) {
  int e = blockIdx.x * blockDim.x + threadIdx.x;
  if (e < EVV) {
    int s = vv_s[e], d = vv_d[e];
    if (s != d) atomicAdd(&cnt_all[d], 1u);            // v2v drops raw self-edges
  } else if (e < EVV + EVI) {
    atomicAdd(&cnt_all[NV + vi_d[e - EVV]], 1u);
  } else if (e < EVV + EVI + EIV) {
    atomicAdd(&cnt_all[NV + NR + iv_d[e - EVV - EVI]], 1u);
  }
}

// 3 blocks, one per topology; wave-shuffle scan, 2 barriers total.
__global__ void scan3_kernel(const unsigned* __restrict__ cnt_all, unsigned* __restrict__ rp_all) {
  int b = blockIdx.x;
  int n = (b == 1) ? NR : NV;
  int cb = (b == 0) ? 0 : (b == 1) ? NV : NV + NR;
  int rb = (b == 0) ? 0 : (b == 1) ? NV + 1 : NV + NR + 2;
  const unsigned* cnt = cnt_all + cb;
  unsigned* rp = rp_all + rb;
  int t = threadIdx.x, lane = t & 63, wid = t >> 6;
  int chunk = (n + 1023) >> 10;
  int beg = t * chunk, end = min(beg + chunk, n);
  int s = 0;
  for (int i = beg; i < end; ++i) s += (int)cnt[i];
  int own = s;
  #pragma unroll
  for (int off = 1; off < 64; off <<= 1) {
    int v = __shfl_up(s, off, 64);
    if (lane >= off) s += v;
  }
  __shared__ int wtot[16], wbase[17];
  if (lane == 63) wtot[wid] = s;
  __syncthreads();
  if (t == 0) {
    int acc = 0;
    #pragma unroll
    for (int w = 0; w < 16; ++w) { wbase[w] = acc; acc += wtot[w]; }
    wbase[16] = acc;
  }
  __syncthreads();
  unsigned base = (unsigned)(wbase[wid] + (s - own));
  for (int i = beg; i < end; ++i) { rp[i] = base; base += cnt[i]; }
  if (t == 0) rp[n] = (unsigned)wbase[16];
}

__global__ void fill_all_kernel(const int* __restrict__ vv_s, const int* __restrict__ vv_d,
                                const int* __restrict__ vi_s, const int* __restrict__ vi_d,
                                const int* __restrict__ iv_s, const int* __restrict__ iv_d,
                                unsigned* __restrict__ cursor_all, int* __restrict__ src_all) {
  int e = blockIdx.x * blockDim.x + threadIdx.x;
  if (e < EVV) {
    int s = vv_s[e], d = vv_d[e];
    if (s == d) return;
    unsigned pos = atomicAdd(&cursor_all[d], 1u);
    src_all[pos] = s;
  } else if (e < EVV + EVI) {
    int i = e - EVV;
    unsigned pos = atomicAdd(&cursor_all[(NV + 1) + vi_d[i]], 1u);
    src_all[EVV + pos] = vi_s[i];
  } else if (e < EVV + EVI + EIV) {
    int i = e - EVV - EVI;
    unsigned pos = atomicAdd(&cursor_all[(NV + NR + 2) + iv_d[i]], 1u);
    src_all[EVV + EVI + pos] = iv_s[i];
  }
}

// ---------------- online softmax step ----------------
template <int CC>
__device__ __forceinline__ void online_update(float pl, float hrv, float a,
                                              float& m, float& s, float& acc) {
  float v = pl + hrv;
  v = (v >= 0.f) ? v : 0.2f * v;                 // leaky_relu(0.2)
  float e = v * a;
  #pragma unroll
  for (int off = CC >> 1; off > 0; off >>= 1) e += __shfl_xor(e, off, 64);
  float nm = fmaxf(m, e);
  float f = __expf(m - nm);                      // m=-inf first iter -> 0
  float w = __expf(e - nm);
  s = s * f + w;
  acc = acc * f + w * pl;
  m = nm;
}

// ---------------- layer-1 gather: projections computed inline (d<=6) ----------------
// lane = h*32+c (heads=2, C=32). nloop: dst<nloop gets a self-loop (src idx = d in xs).
template <int WPD, int DL, int DR, int ADD>
__global__ void gat1_kernel(const unsigned* __restrict__ rp, const int* __restrict__ srcs,
                            const float* __restrict__ xs, const float* __restrict__ xd,
                            const float* __restrict__ Wl, const float* __restrict__ bl_,
                            const float* __restrict__ Wr, const float* __restrict__ br_,
                            const float* __restrict__ att, float* __restrict__ out,
                            int n_dst, int nloop) {
  int lane = threadIdx.x & 63, wid = threadIdx.x >> 6;
  int d = (WPD == 1) ? (blockIdx.x * 4 + wid) : blockIdx.x;
  if (d >= n_dst) return;
  float wl[DL], wr[DR];
  #pragma unroll
  for (int k = 0; k < DL; ++k) wl[k] = Wl[k * 64 + lane];
  #pragma unroll
  for (int k = 0; k < DR; ++k) wr[k] = Wr[k * 64 + lane];
  float blv = bl_[lane], a = att[lane];
  float hrv = br_[lane];
  #pragma unroll
  for (int k = 0; k < DR; ++k) hrv = fmaf(xd[(size_t)d * DR + k], wr[k], hrv);
  float m = -INFINITY, s = 0.f, acc = 0.f;
  unsigned beg = rp[d], end = rp[d + 1];
  for (unsigned i = beg + (WPD == 1 ? 0u : (unsigned)wid); i < end; i += WPD) {
    int sv = srcs[i];
    float pl = blv;
    #pragma unroll
    for (int k = 0; k < DL; ++k) pl = fmaf(xs[(size_t)sv * DL + k], wl[k], pl);
    online_update<32>(pl, hrv, a, m, s, acc);
  }
  if ((WPD == 1 || wid == 0) && d < nloop) {
    float pl = blv;
    #pragma unroll
    for (int k = 0; k < DL; ++k) pl = fmaf(xs[(size_t)d * DL + k], wl[k], pl);
    online_update<32>(pl, hrv, a, m, s, acc);
  }
  if constexpr (WPD == 1) {
    float r = acc / (s + 1e-16f);
    size_t o = (size_t)d * 64 + lane;
    out[o] = ADD ? out[o] + r : r;
  } else {
    __shared__ float sm[4][64], ss[4][64], sacc[4][64];
    sm[wid][lane] = m; ss[wid][lane] = s; sacc[wid][lane] = acc;
    __syncthreads();
    if (wid == 0) {
      float M = -INFINITY;
      #pragma unroll
      for (int w2 = 0; w2 < 4; ++w2) M = fmaxf(M, sm[w2][lane]);
      float S = 0.f, A = 0.f;
      #pragma unroll
      for (int w2 = 0; w2 < 4; ++w2) {
        float mw = sm[w2][lane];
        float f = (mw == -INFINITY) ? 0.f : __expf(mw - M);
        S += ss[w2][lane] * f;
        A += sacc[w2][lane] * f;
      }
      float r = A / (S + 1e-16f);
      size_t o = (size_t)d * 64 + lane;
      out[o] = ADD ? out[o] + r : r;
    }
  }
}

// ---------------- layer-2 gather: precomputed hl/hr tables (heads=1, C=64) ----------------
template <int WPD, int ADD, int SELFMASK>
__global__ void gat2_kernel(const unsigned* __restrict__ rp, const int* __restrict__ srcs,
                            const float* __restrict__ hl, const float* __restrict__ hr,
                            const float* __restrict__ att, float* __restrict__ out,
                            int n_dst, int nloop) {
  int lane = threadIdx.x & 63, wid = threadIdx.x >> 6;
  int d = (WPD == 1) ? (blockIdx.x * 4 + wid) : blockIdx.x;
  if (d >= n_dst) return;
  float a = att[lane];
  float hrv = hr[(size_t)d * 64 + lane];
  float m = -INFINITY, s = 0.f, acc = 0.f;
  unsigned beg = rp[d], end = rp[d + 1];
  for (unsigned i = beg + (WPD == 1 ? 0u : (unsigned)wid); i < end; i += WPD) {
    int sv = srcs[i];
    if (SELFMASK && sv == d) continue;
    float pl = hl[(size_t)sv * 64 + lane];
    online_update<64>(pl, hrv, a, m, s, acc);
  }
  if ((WPD == 1 || wid == 0) && d < nloop) {
    float pl = hl[(size_t)d * 64 + lane];
    online_update<64>(pl, hrv, a, m, s, acc);
  }
  if constexpr (WPD == 1) {
    float r = acc / (s + 1e-16f);
    size_t o = (size_t)d * 64 + lane;
    out[o] = ADD ? out[o] + r : r;
  } else {
    __shared__ float sm[4][64], ss[4][64], sacc[4][64];
    sm[wid][lane] = m; ss[wid][lane] = s; sacc[wid][lane] = acc;
    __syncthreads();
    if (wid == 0) {
      float M = -INFINITY;
      #pragma unroll
      for (int w2 = 0; w2 < 4; ++w2) M = fmaxf(M, sm[w2][lane]);
      float S = 0.f, A = 0.f;
      #pragma unroll
      for (int w2 = 0; w2 < 4; ++w2) {
        float mw = sm[w2][lane];
        float f = (mw == -INFINITY) ? 0.f : __expf(mw - M);
        S += ss[w2][lane] * f;
        A += sacc[w2][lane] * f;
      }
      float r = A / (S + 1e-16f);
      size_t o = (size_t)d * 64 + lane;
      out[o] = ADD ? out[o] + r : r;
    }
  }
}

// ---------------- fused dual projection: out{0,1}[n,64] = x[n,64] @ W{0,1} + b{0,1} ----------------
// block = 256 = 4 waves; wave owns 8 rows; lane = output col. W staged in LDS.
__global__ void proj2_kernel(const float* __restrict__ x,
                             const float* __restrict__ W0, const float* __restrict__ b0,
                             const float* __restrict__ W1, const float* __restrict__ b1,
                             float* __restrict__ out0, float* __restrict__ out1, int n) {
  __shared__ float w0s[4096], w1s[4096];
  int t = threadIdx.x;
  for (int i = t; i < 4096; i += 256) { w0s[i] = W0[i]; w1s[i] = W1[i]; }
  __syncthreads();
  int lane = t & 63, wid = t >> 6;
  int r0 = blockIdx.x * 32 + wid * 8;
  float acc0[8], acc1[8];
  #pragma unroll
  for (int r = 0; r < 8; ++r) { acc0[r] = 0.f; acc1[r] = 0.f; }
  for (int k = 0; k < 64; k += 4) {
    float4 xv[8];
    #pragma unroll
    for (int r = 0; r < 8; ++r) {
      int row = r0 + r;
      xv[r] = (row < n) ? *(const float4*)&x[(size_t)row * 64 + k]
                        : make_float4(0.f, 0.f, 0.f, 0.f);
    }
    #pragma unroll
    for (int j = 0; j < 4; ++j) {
      float w0v = w0s[(k + j) * 64 + lane];
      float w1v = w1s[(k + j) * 64 + lane];
      #pragma unroll
      for (int r = 0; r < 8; ++r) {
        float xvj = (j == 0) ? xv[r].x : (j == 1) ? xv[r].y : (j == 2) ? xv[r].z : xv[r].w;
        acc0[r] = fmaf(xvj, w0v, acc0[r]);
        acc1[r] = fmaf(xvj, w1v, acc1[r]);
      }
    }
  }
  float b0v = b0[lane], b1v = b1[lane];
  #pragma unroll
  for (int r = 0; r < 8; ++r) {
    int row = r0 + r;
    if (row < n) {
      out0[(size_t)row * 64 + lane] = acc0[r] + b0v;
      out1[(size_t)row * 64 + lane] = acc1[r] + b1v;
    }
  }
}

// ---------------- epilogues ----------------
__global__ void elu_bias_kernel(float* __restrict__ x, const float* __restrict__ b1,
                                const float* __restrict__ b2, int n) {
  int t = blockIdx.x * blockDim.x + threadIdx.x;
  if (t >= n * 64) return;
  int col = t & 63;
  float v = x[t] + b1[col] + (b2 ? b2[col] : 0.f);
  x[t] = (v > 0.f) ? v : expm1f(v);
}

__global__ void ln_kernel(const float* __restrict__ acc, const float* __restrict__ b1,
                          const float* __restrict__ b2,
                          const float* __restrict__ lw, const float* __restrict__ lb,
                          float* __restrict__ out, int n) {
  int lane = threadIdx.x & 63;
  int row = blockIdx.x * (blockDim.x >> 6) + (threadIdx.x >> 6);
  if (row >= n) return;
  float v = acc[row * 64 + lane] + b1[lane] + (b2 ? b2[lane] : 0.f);
  float s = v;
  #pragma unroll
  for (int off = 32; off > 0; off >>= 1) s += __shfl_xor(s, off, 64);
  float mu = s * (1.f / 64.f);
  float dv = v - mu;
  float q = dv * dv;
  #pragma unroll
  for (int off = 32; off > 0; off >>= 1) q += __shfl_xor(q, off, 64);
  float var = q * (1.f / 64.f);
  out[row * 64 + lane] = dv * rsqrtf(var + 1e-5f) * lw[lane] + lb[lane];
}

extern "C" void kernel_launch(void* const* d_in, const int* in_sizes, int n_in,
                              void* d_out, int out_size, void* d_ws, size_t ws_size,
                              hipStream_t stream) {
  const float* x_veh = (const float*)d_in[0];
  const float* x_rsu = (const float*)d_in[1];
  const int* ei_v2v = (const int*)d_in[2];
  const int* ei_v2i = (const int*)d_in[3];
  const int* ei_i2v = (const int*)d_in[4];
  const float* P[36];
  for (int i = 0; i < 36; ++i) P[i] = (const float*)d_in[5 + i];
  // blocks of 6 (Wl, bl, Wr, br, att, b):
  // p1v P[0..5], p1i P[6..11], p1r P[12..17], p2v P[18..23], p2i P[24..29], p2r P[30..35]
  const float* lnv_w = (const float*)d_in[41];
  const float* lnv_b = (const float*)d_in[42];
  const float* lnr_w = (const float*)d_in[43];
  const float* lnr_b = (const float*)d_in[44];

  float* ws = (float*)d_ws;
  float* P0    = ws;
  float* P1    = P0 + 3200000;
  float* ACCV  = P1 + 3200000;         // h_veh
  float* ACC2V = ACCV + 3200000;
  float* S0    = ACC2V + 3200000;      // 32000
  float* S1    = S0 + 32000;
  float* ACCR  = S1 + 32000;           // h_rsu
  float* ACC2R = ACCR + 32000;
  unsigned* cnt_all    = (unsigned*)(ACC2R + 32000);   // NV+NR+NV = 100500
  unsigned* rp_all     = cnt_all + 100500;             // 100503
  unsigned* cursor_all = rp_all + 100503;              // 100503
  int* src_all         = (int*)(cursor_all + 100503);  // 600000
  // total ~55.3 MB

  const unsigned* rp_vv = rp_all;
  const unsigned* rp_vi = rp_all + NV + 1;
  const unsigned* rp_iv = rp_all + NV + NR + 2;
  const int* src_vv = src_all;
  const int* src_vi = src_all + EVV;
  const int* src_iv = src_all + EVV + EVI;

  auto gsz = [](int n) { return (n + 255) / 256; };
  auto gsz4 = [](int n) { return (n + 3) / 4; };       // 4 dst-waves per block
  auto gszr = [](int n) { return (n + 31) / 32; };     // proj2: 32 rows per block

  // ---- CSR build (one pass over all 600k edges) ----
  hipMemsetAsync(cnt_all, 0, 100500u * 4, stream);
  hist_all_kernel<<<gsz(EVV + EVI + EIV), 256, 0, stream>>>(
      ei_v2v, ei_v2v + EVV, ei_v2i + EVI, ei_i2v + EIV, cnt_all);
  scan3_kernel<<<3, 1024, 0, stream>>>(cnt_all, rp_all);
  hipMemcpyAsync(cursor_all, rp_all, 100503u * 4, hipMemcpyDeviceToDevice, stream);
  fill_all_kernel<<<gsz(EVV + EVI + EIV), 256, 0, stream>>>(
      ei_v2v, ei_v2v + EVV, ei_v2i, ei_v2i + EVI, ei_i2v, ei_i2v + EIV, cursor_all, src_all);

  // ---- layer 1 (heads=2, C=32; projections inline, no proj kernels) ----
  gat1_kernel<1, 6, 6, 0><<<gsz4(NV), 256, 0, stream>>>(
      rp_vv, src_vv, x_veh, x_veh, P[0], P[1], P[2], P[3], P[4], ACCV, NV, NV);
  gat1_kernel<1, 1, 6, 1><<<gsz4(NV), 256, 0, stream>>>(
      rp_iv, src_iv, x_rsu, x_veh, P[12], P[13], P[14], P[15], P[16], ACCV, NV, 0);
  elu_bias_kernel<<<gsz(NV * 64), 256, 0, stream>>>(ACCV, P[5], P[17], NV);
  gat1_kernel<4, 6, 1, 0><<<NR, 256, 0, stream>>>(
      rp_vi, src_vi, x_veh, x_rsu, P[6], P[7], P[8], P[9], P[10], ACCR, NR, 0);
  elu_bias_kernel<<<gsz(NR * 64), 256, 0, stream>>>(ACCR, P[11], nullptr, NR);

  // ---- layer 2 (heads=1, C=64) ----
  proj2_kernel<<<gszr(NV), 256, 0, stream>>>(ACCV, P[18], P[19], P[20], P[21], P0, P1, NV);
  proj2_kernel<<<gszr(NR), 256, 0, stream>>>(ACCR, P[30], P[31], P[26], P[27], S0, S1, NR);
  gat2_kernel<1, 0, 0><<<gsz4(NV), 256, 0, stream>>>(
      rp_vv, src_vv, P0, P1, P[22], ACC2V, NV, NV);
  proj2_kernel<<<gszr(NV), 256, 0, stream>>>(ACCV, P[32], P[33], P[24], P[25], P1, P0, NV);
  gat2_kernel<1, 1, 1><<<gsz4(NV), 256, 0, stream>>>(
      rp_iv, src_iv, S0, P1, P[34], ACC2V, NV, NR);
  ln_kernel<<<gsz(NV * 64), 256, 0, stream>>>(ACC2V, P[23], P[35], lnv_w, lnv_b,
                                              (float*)d_out, NV);
  gat2_kernel<4, 0, 1><<<NR, 256, 0, stream>>>(
      rp_vi, src_vi, P0, S1, P[28], ACC2R, NR, NR);
  ln_kernel<<<gsz(NR * 64), 256, 0, stream>>>(ACC2R, P[29], nullptr, lnr_w, lnr_b,
                                              (float*)d_out + (size_t)NV * 64, NR);
}

// Round 4
// 497.357 us; speedup vs baseline: 3.8866x; 3.8866x over previous
//
#include <hip/hip_runtime.h>
#include <math.h>

#define NV 50000
#define NR 500
#define EVV 400000
#define EVI 100000
#define EIV 100000

// ---------------- CSR build (batched over all 3 topologies) ----------------
// cnt_all layout: [vv: NV][vi: NR][iv: NV]
// rp_all  layout: [vv: NV+1][vi: NR+1][iv: NV+1]
// src_all layout: [vv: EVV][vi: EVI][iv: EIV]
__global__ void hist_all_kernel(const int* __restrict__ vv_s, const int* __restrict__ vv_d,
                                const int* __restrict__ vi_d, const int* __restrict__ iv_d,
                                unsigned* __restrict__ cnt_all) {
  int e = blockIdx.x * blockDim.x + threadIdx.x;
  if (e < EVV) {
    int s = vv_s[e], d = vv_d[e];
    if (s != d) atomicAdd(&cnt_all[d], 1u);            // v2v drops raw self-edges
  } else if (e < EVV + EVI) {
    atomicAdd(&cnt_all[NV + vi_d[e - EVV]], 1u);
  } else if (e < EVV + EVI + EIV) {
    atomicAdd(&cnt_all[NV + NR + iv_d[e - EVV - EVI]], 1u);
  }
}

// 3 blocks, one per topology; wave-shuffle scan, 2 barriers total.
__global__ void scan3_kernel(const unsigned* __restrict__ cnt_all, unsigned* __restrict__ rp_all) {
  int b = blockIdx.x;
  int n = (b == 1) ? NR : NV;
  int cb = (b == 0) ? 0 : (b == 1) ? NV : NV + NR;
  int rb = (b == 0) ? 0 : (b == 1) ? NV + 1 : NV + NR + 2;
  const unsigned* cnt = cnt_all + cb;
  unsigned* rp = rp_all + rb;
  int t = threadIdx.x, lane = t & 63, wid = t >> 6;
  int chunk = (n + 1023) >> 10;
  int beg = t * chunk, end = min(beg + chunk, n);
  int s = 0;
  for (int i = beg; i < end; ++i) s += (int)cnt[i];
  int own = s;
  #pragma unroll
  for (int off = 1; off < 64; off <<= 1) {
    int v = __shfl_up(s, off, 64);
    if (lane >= off) s += v;
  }
  __shared__ int wtot[16], wbase[17];
  if (lane == 63) wtot[wid] = s;
  __syncthreads();
  if (t == 0) {
    int acc = 0;
    #pragma unroll
    for (int w = 0; w < 16; ++w) { wbase[w] = acc; acc += wtot[w]; }
    wbase[16] = acc;
  }
  __syncthreads();
  unsigned base = (unsigned)(wbase[wid] + (s - own));
  for (int i = beg; i < end; ++i) { rp[i] = base; base += cnt[i]; }
  if (t == 0) rp[n] = (unsigned)wbase[16];
}

__global__ void fill_all_kernel(const int* __restrict__ vv_s, const int* __restrict__ vv_d,
                                const int* __restrict__ vi_s, const int* __restrict__ vi_d,
                                const int* __restrict__ iv_s, const int* __restrict__ iv_d,
                                unsigned* __restrict__ cursor_all, int* __restrict__ src_all) {
  int e = blockIdx.x * blockDim.x + threadIdx.x;
  if (e < EVV) {
    int s = vv_s[e], d = vv_d[e];
    if (s == d) return;
    unsigned pos = atomicAdd(&cursor_all[d], 1u);
    src_all[pos] = s;
  } else if (e < EVV + EVI) {
    int i = e - EVV;
    unsigned pos = atomicAdd(&cursor_all[(NV + 1) + vi_d[i]], 1u);
    src_all[EVV + pos] = vi_s[i];
  } else if (e < EVV + EVI + EIV) {
    int i = e - EVV - EVI;
    unsigned pos = atomicAdd(&cursor_all[(NV + NR + 2) + iv_d[i]], 1u);
    src_all[EVV + EVI + pos] = iv_s[i];
  }
}

// ---------------- online softmax step ----------------
template <int CC>
__device__ __forceinline__ void online_update(float pl, float hrv, float a,
                                              float& m, float& s, float& acc) {
  float v = pl + hrv;
  v = (v >= 0.f) ? v : 0.2f * v;                 // leaky_relu(0.2)
  float e = v * a;
  #pragma unroll
  for (int off = CC >> 1; off > 0; off >>= 1) e += __shfl_xor(e, off, 64);
  float nm = fmaxf(m, e);
  float f = __expf(m - nm);                      // m=-inf first iter -> 0
  float w = __expf(e - nm);
  s = s * f + w;
  acc = acc * f + w * pl;
  m = nm;
}

// ---------------- layer-1 gather: projections computed inline (d<=6) ----------------
// lane = h*32+c (heads=2, C=32). nloop: dst<nloop gets a self-loop (src idx = d in xs).
template <int WPD, int DL, int DR, int ADD>
__global__ void gat1_kernel(const unsigned* __restrict__ rp, const int* __restrict__ srcs,
                            const float* __restrict__ xs, const float* __restrict__ xd,
                            const float* __restrict__ Wl, const float* __restrict__ bl_,
                            const float* __restrict__ Wr, const float* __restrict__ br_,
                            const float* __restrict__ att, float* __restrict__ out,
                            int n_dst, int nloop) {
  int lane = threadIdx.x & 63, wid = threadIdx.x >> 6;
  int d = (WPD == 1) ? (blockIdx.x * 4 + wid) : blockIdx.x;
  if (d >= n_dst) return;
  float wl[DL], wr[DR];
  #pragma unroll
  for (int k = 0; k < DL; ++k) wl[k] = Wl[k * 64 + lane];
  #pragma unroll
  for (int k = 0; k < DR; ++k) wr[k] = Wr[k * 64 + lane];
  float blv = bl_[lane], a = att[lane];
  float hrv = br_[lane];
  #pragma unroll
  for (int k = 0; k < DR; ++k) hrv = fmaf(xd[(size_t)d * DR + k], wr[k], hrv);
  float m = -INFINITY, s = 0.f, acc = 0.f;
  unsigned beg = rp[d], end = rp[d + 1];
  for (unsigned i = beg + (WPD == 1 ? 0u : (unsigned)wid); i < end; i += WPD) {
    int sv = srcs[i];
    float pl = blv;
    #pragma unroll
    for (int k = 0; k < DL; ++k) pl = fmaf(xs[(size_t)sv * DL + k], wl[k], pl);
    online_update<32>(pl, hrv, a, m, s, acc);
  }
  if ((WPD == 1 || wid == 0) && d < nloop) {
    float pl = blv;
    #pragma unroll
    for (int k = 0; k < DL; ++k) pl = fmaf(xs[(size_t)d * DL + k], wl[k], pl);
    online_update<32>(pl, hrv, a, m, s, acc);
  }
  if constexpr (WPD == 1) {
    float r = acc / (s + 1e-16f);
    size_t o = (size_t)d * 64 + lane;
    out[o] = ADD ? out[o] + r : r;
  } else {
    __shared__ float sm[4][64], ss[4][64], sacc[4][64];
    sm[wid][lane] = m; ss[wid][lane] = s; sacc[wid][lane] = acc;
    __syncthreads();
    if (wid == 0) {
      float M = -INFINITY;
      #pragma unroll
      for (int w2 = 0; w2 < 4; ++w2) M = fmaxf(M, sm[w2][lane]);
      float S = 0.f, A = 0.f;
      #pragma unroll
      for (int w2 = 0; w2 < 4; ++w2) {
        float mw = sm[w2][lane];
        float f = (mw == -INFINITY) ? 0.f : __expf(mw - M);
        S += ss[w2][lane] * f;
        A += sacc[w2][lane] * f;
      }
      float r = A / (S + 1e-16f);
      size_t o = (size_t)d * 64 + lane;
      out[o] = ADD ? out[o] + r : r;
    }
  }
}

// ---------------- layer-2 gather: precomputed hl/hr tables (heads=1, C=64) ----------------
template <int WPD, int ADD, int SELFMASK>
__global__ void gat2_kernel(const unsigned* __restrict__ rp, const int* __restrict__ srcs,
                            const float* __restrict__ hl, const float* __restrict__ hr,
                            const float* __restrict__ att, float* __restrict__ out,
                            int n_dst, int nloop) {
  int lane = threadIdx.x & 63, wid = threadIdx.x >> 6;
  int d = (WPD == 1) ? (blockIdx.x * 4 + wid) : blockIdx.x;
  if (d >= n_dst) return;
  float a = att[lane];
  float hrv = hr[(size_t)d * 64 + lane];
  float m = -INFINITY, s = 0.f, acc = 0.f;
  unsigned beg = rp[d], end = rp[d + 1];
  for (unsigned i = beg + (WPD == 1 ? 0u : (unsigned)wid); i < end; i += WPD) {
    int sv = srcs[i];
    if (SELFMASK && sv == d) continue;
    float pl = hl[(size_t)sv * 64 + lane];
    online_update<64>(pl, hrv, a, m, s, acc);
  }
  if ((WPD == 1 || wid == 0) && d < nloop) {
    float pl = hl[(size_t)d * 64 + lane];
    online_update<64>(pl, hrv, a, m, s, acc);
  }
  if constexpr (WPD == 1) {
    float r = acc / (s + 1e-16f);
    size_t o = (size_t)d * 64 + lane;
    out[o] = ADD ? out[o] + r : r;
  } else {
    __shared__ float sm[4][64], ss[4][64], sacc[4][64];
    sm[wid][lane] = m; ss[wid][lane] = s; sacc[wid][lane] = acc;
    __syncthreads();
    if (wid == 0) {
      float M = -INFINITY;
      #pragma unroll
      for (int w2 = 0; w2 < 4; ++w2) M = fmaxf(M, sm[w2][lane]);
      float S = 0.f, A = 0.f;
      #pragma unroll
      for (int w2 = 0; w2 < 4; ++w2) {
        float mw = sm[w2][lane];
        float f = (mw == -INFINITY) ? 0.f : __expf(mw - M);
        S += ss[w2][lane] * f;
        A += sacc[w2][lane] * f;
      }
      float r = A / (S + 1e-16f);
      size_t o = (size_t)d * 64 + lane;
      out[o] = ADD ? out[o] + r : r;
    }
  }
}

// ---------------- fused dual projection: out{0,1}[n,64] = x[n,64] @ W{0,1} + b{0,1} ----------------
// block = 256 = 4 waves; 32 rows/block (8/wave); W0,W1 AND the x-tile staged in LDS.
// Inner loop: named scalars only (no register aggregates w/ conditionals) -> no scratch.
__global__ __launch_bounds__(256, 2)
void proj2_kernel(const float* __restrict__ x,
                  const float* __restrict__ W0, const float* __restrict__ b0,
                  const float* __restrict__ W1, const float* __restrict__ b1,
                  float* __restrict__ out0, float* __restrict__ out1, int n) {
  __shared__ float w0s[4096], w1s[4096], xtile[2048];   // 40 KB
  int t = threadIdx.x;
  for (int i = t; i < 4096; i += 256) { w0s[i] = W0[i]; w1s[i] = W1[i]; }
  int base = blockIdx.x * 32;
  for (int i = t; i < 2048; i += 256) {
    int row = base + (i >> 6);
    int rc = (row < n) ? row : (n - 1);                 // clamp: scalar select, no vector cmov
    xtile[i] = x[(size_t)rc * 64 + (i & 63)];
  }
  __syncthreads();
  int lane = t & 63, wid = t >> 6;
  int wr = wid * 8;                                     // wave's first row in tile
  float acc0[8], acc1[8];
  #pragma unroll
  for (int r = 0; r < 8; ++r) { acc0[r] = 0.f; acc1[r] = 0.f; }
  for (int kq = 0; kq < 16; ++kq) {
    int k = kq * 4;
    float w00 = w0s[(k + 0) * 64 + lane];
    float w01 = w0s[(k + 1) * 64 + lane];
    float w02 = w0s[(k + 2) * 64 + lane];
    float w03 = w0s[(k + 3) * 64 + lane];
    float w10 = w1s[(k + 0) * 64 + lane];
    float w11 = w1s[(k + 1) * 64 + lane];
    float w12 = w1s[(k + 2) * 64 + lane];
    float w13 = w1s[(k + 3) * 64 + lane];
    #pragma unroll
    for (int r = 0; r < 8; ++r) {
      float4 xv = *(const float4*)&xtile[(wr + r) * 64 + k];   // wave-uniform ds_read_b128
      acc0[r] = fmaf(xv.x, w00, acc0[r]);
      acc0[r] = fmaf(xv.y, w01, acc0[r]);
      acc0[r] = fmaf(xv.z, w02, acc0[r]);
      acc0[r] = fmaf(xv.w, w03, acc0[r]);
      acc1[r] = fmaf(xv.x, w10, acc1[r]);
      acc1[r] = fmaf(xv.y, w11, acc1[r]);
      acc1[r] = fmaf(xv.z, w12, acc1[r]);
      acc1[r] = fmaf(xv.w, w13, acc1[r]);
    }
  }
  float b0v = b0[lane], b1v = b1[lane];
  #pragma unroll
  for (int r = 0; r < 8; ++r) {
    int row = base + wr + r;
    if (row < n) {
      out0[(size_t)row * 64 + lane] = acc0[r] + b0v;
      out1[(size_t)row * 64 + lane] = acc1[r] + b1v;
    }
  }
}

// ---------------- epilogues ----------------
__global__ void elu_bias_kernel(float* __restrict__ x, const float* __restrict__ b1,
                                const float* __restrict__ b2, int n) {
  int t = blockIdx.x * blockDim.x + threadIdx.x;
  if (t >= n * 64) return;
  int col = t & 63;
  float v = x[t] + b1[col] + (b2 ? b2[col] : 0.f);
  x[t] = (v > 0.f) ? v : expm1f(v);
}

__global__ void ln_kernel(const float* __restrict__ acc, const float* __restrict__ b1,
                          const float* __restrict__ b2,
                          const float* __restrict__ lw, const float* __restrict__ lb,
                          float* __restrict__ out, int n) {
  int lane = threadIdx.x & 63;
  int row = blockIdx.x * (blockDim.x >> 6) + (threadIdx.x >> 6);
  if (row >= n) return;
  float v = acc[row * 64 + lane] + b1[lane] + (b2 ? b2[lane] : 0.f);
  float s = v;
  #pragma unroll
  for (int off = 32; off > 0; off >>= 1) s += __shfl_xor(s, off, 64);
  float mu = s * (1.f / 64.f);
  float dv = v - mu;
  float q = dv * dv;
  #pragma unroll
  for (int off = 32; off > 0; off >>= 1) q += __shfl_xor(q, off, 64);
  float var = q * (1.f / 64.f);
  out[row * 64 + lane] = dv * rsqrtf(var + 1e-5f) * lw[lane] + lb[lane];
}

extern "C" void kernel_launch(void* const* d_in, const int* in_sizes, int n_in,
                              void* d_out, int out_size, void* d_ws, size_t ws_size,
                              hipStream_t stream) {
  const float* x_veh = (const float*)d_in[0];
  const float* x_rsu = (const float*)d_in[1];
  const int* ei_v2v = (const int*)d_in[2];
  const int* ei_v2i = (const int*)d_in[3];
  const int* ei_i2v = (const int*)d_in[4];
  const float* P[36];
  for (int i = 0; i < 36; ++i) P[i] = (const float*)d_in[5 + i];
  // blocks of 6 (Wl, bl, Wr, br, att, b):
  // p1v P[0..5], p1i P[6..11], p1r P[12..17], p2v P[18..23], p2i P[24..29], p2r P[30..35]
  const float* lnv_w = (const float*)d_in[41];
  const float* lnv_b = (const float*)d_in[42];
  const float* lnr_w = (const float*)d_in[43];
  const float* lnr_b = (const float*)d_in[44];

  float* ws = (float*)d_ws;
  float* P0    = ws;
  float* P1    = P0 + 3200000;
  float* ACCV  = P1 + 3200000;         // h_veh
  float* ACC2V = ACCV + 3200000;
  float* S0    = ACC2V + 3200000;      // 32000
  float* S1    = S0 + 32000;
  float* ACCR  = S1 + 32000;           // h_rsu
  float* ACC2R = ACCR + 32000;
  unsigned* cnt_all    = (unsigned*)(ACC2R + 32000);   // NV+NR+NV = 100500
  unsigned* rp_all     = cnt_all + 100500;             // 100503
  unsigned* cursor_all = rp_all + 100503;              // 100503
  int* src_all         = (int*)(cursor_all + 100503);  // 600000
  // total ~55.3 MB

  const unsigned* rp_vv = rp_all;
  const unsigned* rp_vi = rp_all + NV + 1;
  const unsigned* rp_iv = rp_all + NV + NR + 2;
  const int* src_vv = src_all;
  const int* src_vi = src_all + EVV;
  const int* src_iv = src_all + EVV + EVI;

  auto gsz = [](int n) { return (n + 255) / 256; };
  auto gsz4 = [](int n) { return (n + 3) / 4; };       // 4 dst-waves per block
  auto gszr = [](int n) { return (n + 31) / 32; };     // proj2: 32 rows per block

  // ---- CSR build (one pass over all 600k edges) ----
  hipMemsetAsync(cnt_all, 0, 100500u * 4, stream);
  hist_all_kernel<<<gsz(EVV + EVI + EIV), 256, 0, stream>>>(
      ei_v2v, ei_v2v + EVV, ei_v2i + EVI, ei_i2v + EIV, cnt_all);
  scan3_kernel<<<3, 1024, 0, stream>>>(cnt_all, rp_all);
  hipMemcpyAsync(cursor_all, rp_all, 100503u * 4, hipMemcpyDeviceToDevice, stream);
  fill_all_kernel<<<gsz(EVV + EVI + EIV), 256, 0, stream>>>(
      ei_v2v, ei_v2v + EVV, ei_v2i, ei_v2i + EVI, ei_i2v, ei_i2v + EIV, cursor_all, src_all);

  // ---- layer 1 (heads=2, C=32; projections inline, no proj kernels) ----
  gat1_kernel<1, 6, 6, 0><<<gsz4(NV), 256, 0, stream>>>(
      rp_vv, src_vv, x_veh, x_veh, P[0], P[1], P[2], P[3], P[4], ACCV, NV, NV);
  gat1_kernel<1, 1, 6, 1><<<gsz4(NV), 256, 0, stream>>>(
      rp_iv, src_iv, x_rsu, x_veh, P[12], P[13], P[14], P[15], P[16], ACCV, NV, 0);
  elu_bias_kernel<<<gsz(NV * 64), 256, 0, stream>>>(ACCV, P[5], P[17], NV);
  gat1_kernel<4, 6, 1, 0><<<NR, 256, 0, stream>>>(
      rp_vi, src_vi, x_veh, x_rsu, P[6], P[7], P[8], P[9], P[10], ACCR, NR, 0);
  elu_bias_kernel<<<gsz(NR * 64), 256, 0, stream>>>(ACCR, P[11], nullptr, NR);

  // ---- layer 2 (heads=1, C=64) ----
  proj2_kernel<<<gszr(NV), 256, 0, stream>>>(ACCV, P[18], P[19], P[20], P[21], P0, P1, NV);
  proj2_kernel<<<gszr(NR), 256, 0, stream>>>(ACCR, P[30], P[31], P[26], P[27], S0, S1, NR);
  gat2_kernel<1, 0, 0><<<gsz4(NV), 256, 0, stream>>>(
      rp_vv, src_vv, P0, P1, P[22], ACC2V, NV, NV);
  proj2_kernel<<<gszr(NV), 256, 0, stream>>>(ACCV, P[32], P[33], P[24], P[25], P1, P0, NV);
  gat2_kernel<1, 1, 1><<<gsz4(NV), 256, 0, stream>>>(
      rp_iv, src_iv, S0, P1, P[34], ACC2V, NV, NR);
  ln_kernel<<<gsz(NV * 64), 256, 0, stream>>>(ACC2V, P[23], P[35], lnv_w, lnv_b,
                                              (float*)d_out, NV);
  gat2_kernel<4, 0, 1><<<NR, 256, 0, stream>>>(
      rp_vi, src_vi, P0, S1, P[28], ACC2R, NR, NR);
  ln_kernel<<<gsz(NR * 64), 256, 0, stream>>>(ACC2R, P[29], nullptr, lnr_w, lnr_b,
                                              (float*)d_out + (size_t)NV * 64, NR);
}

// Round 5
// 389.357 us; speedup vs baseline: 4.9647x; 1.2774x over previous
//
#include <hip/hip_runtime.h>
#include <math.h>
#include <float.h>

#define NV 50000
#define NR 500
#define EVV 400000
#define EVI 100000
#define EIV 100000

// count-array segment offsets (each 4-aligned)
#define CB_VV 0
#define CB_VI 50000
#define CB_IV 50500
#define CNT_LEN 100500
// rp/cursor segment offsets (each 4-aligned, padded)
#define RB_VV 0
#define RB_VI 50004
#define RB_IV 50508
#define RP_LEN 100512
// scan tiles
#define TILE 1024
#define T_VV 49
#define T_IV 49
#define T_TOT 99   // 49 vv + 1 vi + 49 iv

// ---------------- CSR build ----------------
__global__ void hist_all_kernel(const int* __restrict__ vv_s, const int* __restrict__ vv_d,
                                const int* __restrict__ vi_d, const int* __restrict__ iv_d,
                                unsigned* __restrict__ cnt_all) {
  int e = blockIdx.x * blockDim.x + threadIdx.x;
  if (e < EVV) {
    int s = vv_s[e], d = vv_d[e];
    if (s != d) atomicAdd(&cnt_all[CB_VV + d], 1u);     // v2v drops raw self-edges
  } else if (e < EVV + EVI) {
    atomicAdd(&cnt_all[CB_VI + vi_d[e - EVV]], 1u);
  } else if (e < EVV + EVI + EIV) {
    atomicAdd(&cnt_all[CB_IV + iv_d[e - EVV - EVI]], 1u);
  }
}

__device__ __forceinline__ void tile_decode(int b, int& cb, int& rb, int& n, int& base) {
  int topo = (b < T_VV) ? 0 : (b == T_VV) ? 1 : 2;
  int lt   = (topo == 0) ? b : (topo == 1) ? 0 : b - T_VV - 1;
  cb   = (topo == 0) ? CB_VV : (topo == 1) ? CB_VI : CB_IV;
  rb   = (topo == 0) ? RB_VV : (topo == 1) ? RB_VI : RB_IV;
  n    = (topo == 1) ? NR : NV;
  base = lt * TILE;
}

// 99 blocks x 256: per-tile sum of counts
__global__ void tilesum_kernel(const unsigned* __restrict__ cnt_all, unsigned* __restrict__ tsum) {
  int cb, rb, n, base;
  tile_decode(blockIdx.x, cb, rb, n, base);
  int t = threadIdx.x, lane = t & 63, wid = t >> 6;
  unsigned s = 0;
  #pragma unroll
  for (int j = 0; j < 4; ++j) {
    int i = base + t + j * 256;
    if (i < n) s += cnt_all[cb + i];
  }
  #pragma unroll
  for (int off = 32; off > 0; off >>= 1) s += (unsigned)__shfl_xor((int)s, off, 64);
  __shared__ unsigned wt[4];
  if (lane == 0) wt[wid] = s;
  __syncthreads();
  if (t == 0) tsum[blockIdx.x] = wt[0] + wt[1] + wt[2] + wt[3];
}

// 1 block x 128: exclusive scan of tile sums per topology + totals (rp[n])
__global__ void tilescan_kernel(const unsigned* __restrict__ tsum, unsigned* __restrict__ tbase,
                                unsigned* __restrict__ rp_all) {
  __shared__ unsigned ts[T_TOT];
  int t = threadIdx.x;
  if (t < T_TOT) ts[t] = tsum[t];
  __syncthreads();
  if (t == 0) {
    unsigned a = 0;
    for (int j = 0; j < T_VV; ++j) { tbase[j] = a; a += ts[j]; }
    rp_all[RB_VV + NV] = a;
  } else if (t == 64) {
    tbase[T_VV] = 0;
    rp_all[RB_VI + NR] = ts[T_VV];
  } else if (t == 65) {
    unsigned a = 0;
    for (int j = 0; j < T_IV; ++j) { tbase[T_VV + 1 + j] = a; a += ts[T_VV + 1 + j]; }
    rp_all[RB_IV + NV] = a;
  }
}

// 99 blocks x 256: per-tile block scan -> rp and cursor
__global__ void scanwrite_kernel(const unsigned* __restrict__ cnt_all,
                                 const unsigned* __restrict__ tbase,
                                 unsigned* __restrict__ rp_all,
                                 unsigned* __restrict__ cursor_all) {
  int cb, rb, n, base;
  tile_decode(blockIdx.x, cb, rb, n, base);
  int t = threadIdx.x, lane = t & 63, wid = t >> 6;
  int i0 = base + t * 4;
  unsigned c0 = 0, c1 = 0, c2 = 0, c3 = 0;
  if (i0 + 3 < n) {
    uint4 v = *(const uint4*)&cnt_all[cb + i0];
    c0 = v.x; c1 = v.y; c2 = v.z; c3 = v.w;
  } else if (i0 < n) {
    c0 = cnt_all[cb + i0];
    if (i0 + 1 < n) c1 = cnt_all[cb + i0 + 1];
    if (i0 + 2 < n) c2 = cnt_all[cb + i0 + 2];
  }
  unsigned s4 = c0 + c1 + c2 + c3;
  unsigned inc = s4;
  #pragma unroll
  for (int off = 1; off < 64; off <<= 1) {
    unsigned v = (unsigned)__shfl_up((int)inc, off, 64);
    if (lane >= off) inc += v;
  }
  __shared__ unsigned wt[4];
  if (lane == 63) wt[wid] = inc;
  __syncthreads();
  unsigned wb = tbase[blockIdx.x];
  #pragma unroll
  for (int w = 0; w < 4; ++w) if (w < wid) wb += wt[w];
  unsigned p0 = wb + inc - s4;
  unsigned p1 = p0 + c0, p2 = p1 + c1, p3 = p2 + c2;
  if (i0 + 3 < n) {
    uint4 v = make_uint4(p0, p1, p2, p3);
    *(uint4*)&rp_all[rb + i0] = v;
    *(uint4*)&cursor_all[rb + i0] = v;
  } else if (i0 < n) {
    rp_all[rb + i0] = p0; cursor_all[rb + i0] = p0;
    if (i0 + 1 < n) { rp_all[rb + i0 + 1] = p1; cursor_all[rb + i0 + 1] = p1; }
    if (i0 + 2 < n) { rp_all[rb + i0 + 2] = p2; cursor_all[rb + i0 + 2] = p2; }
  }
}

__global__ void fill_all_kernel(const int* __restrict__ vv_s, const int* __restrict__ vv_d,
                                const int* __restrict__ vi_s, const int* __restrict__ vi_d,
                                const int* __restrict__ iv_s, const int* __restrict__ iv_d,
                                unsigned* __restrict__ cursor_all, int* __restrict__ src_all) {
  int e = blockIdx.x * blockDim.x + threadIdx.x;
  if (e < EVV) {
    int s = vv_s[e], d = vv_d[e];
    if (s == d) return;
    unsigned pos = atomicAdd(&cursor_all[RB_VV + d], 1u);
    src_all[pos] = s;
  } else if (e < EVV + EVI) {
    int i = e - EVV;
    unsigned pos = atomicAdd(&cursor_all[RB_VI + vi_d[i]], 1u);
    src_all[EVV + pos] = vi_s[i];
  } else if (e < EVV + EVI + EIV) {
    int i = e - EVV - EVI;
    unsigned pos = atomicAdd(&cursor_all[RB_IV + iv_d[i]], 1u);
    src_all[EVV + EVI + pos] = iv_s[i];
  }
}

// ---------------- shared epilogue helpers ----------------
__device__ __forceinline__ float ln_row(float v, int lane,
                                        const float* __restrict__ lw,
                                        const float* __restrict__ lb) {
  float sum = v;
  #pragma unroll
  for (int off = 32; off > 0; off >>= 1) sum += __shfl_xor(sum, off, 64);
  float mu = sum * (1.f / 64.f);
  float dv = v - mu;
  float q = dv * dv;
  #pragma unroll
  for (int off = 32; off > 0; off >>= 1) q += __shfl_xor(q, off, 64);
  return dv * rsqrtf(q * (1.f / 64.f) + 1e-5f) * lw[lane] + lb[lane];
}

// ---------------- layer-1 gather (heads=2, C=32), inline projections ----------------
// EPI: 0 plain write; 1 add-old + eb1 + eb2 + elu; 2 (WPD=4) eb1 + elu
template <int WPD, int CHUNK, int DL, int DR, int EPI>
__global__ void gat1_kernel(const unsigned* __restrict__ rp, const int* __restrict__ srcs,
                            const float* __restrict__ xs, const float* __restrict__ xd,
                            const float* __restrict__ Wl, const float* __restrict__ bl_,
                            const float* __restrict__ Wr, const float* __restrict__ br_,
                            const float* __restrict__ att, float* __restrict__ out,
                            const float* __restrict__ eb1, const float* __restrict__ eb2,
                            int n_dst, int nloop) {
  int lane = threadIdx.x & 63, wid = threadIdx.x >> 6;
  int d = (WPD == 1) ? (blockIdx.x * 4 + wid) : blockIdx.x;
  if (d >= n_dst) return;
  float wl[DL], wr[DR];
  #pragma unroll
  for (int k = 0; k < DL; ++k) wl[k] = Wl[k * 64 + lane];
  #pragma unroll
  for (int k = 0; k < DR; ++k) wr[k] = Wr[k * 64 + lane];
  float blv = bl_[lane], a = att[lane];
  float hrv = br_[lane];
  #pragma unroll
  for (int k = 0; k < DR; ++k) hrv = fmaf(xd[(size_t)d * DR + k], wr[k], hrv);
  float m = -INFINITY, s = 0.f, acc = 0.f;
  unsigned beg = rp[d], end = rp[d + 1];
  for (unsigned i = beg + (WPD == 1 ? 0u : (unsigned)(wid * CHUNK)); i < end;
       i += WPD * CHUNK) {
    float pl[CHUNK], e[CHUNK];
    #pragma unroll
    for (int j = 0; j < CHUNK; ++j) {
      unsigned idx = i + j;
      int sv = (idx < end) ? srcs[idx] : 0;
      float p = blv;
      #pragma unroll
      for (int k = 0; k < DL; ++k) p = fmaf(xs[(size_t)sv * DL + k], wl[k], p);
      pl[j] = p;
    }
    #pragma unroll
    for (int j = 0; j < CHUNK; ++j) {
      float v = pl[j] + hrv;
      v = (v >= 0.f) ? v : 0.2f * v;
      float ee = v * a;
      #pragma unroll
      for (int off = 16; off > 0; off >>= 1) ee += __shfl_xor(ee, off, 64);
      e[j] = (i + j < end) ? ee : -INFINITY;
    }
    float cmax = e[0];
    #pragma unroll
    for (int j = 1; j < CHUNK; ++j) cmax = fmaxf(cmax, e[j]);
    float nm = fmaxf(m, cmax);
    float f = (m > -FLT_MAX) ? __expf(m - nm) : 0.f;
    float ssum = 0.f, asum = 0.f;
    #pragma unroll
    for (int j = 0; j < CHUNK; ++j) {
      float w = (e[j] > -FLT_MAX) ? __expf(e[j] - nm) : 0.f;
      ssum += w;
      asum = fmaf(w, pl[j], asum);
    }
    s = s * f + ssum;
    acc = acc * f + asum;
    m = nm;
  }
  if ((WPD == 1 || wid == 0) && d < nloop) {       // self-loop
    float p = blv;
    #pragma unroll
    for (int k = 0; k < DL; ++k) p = fmaf(xs[(size_t)d * DL + k], wl[k], p);
    float v = p + hrv; v = (v >= 0.f) ? v : 0.2f * v;
    float ee = v * a;
    #pragma unroll
    for (int off = 16; off > 0; off >>= 1) ee += __shfl_xor(ee, off, 64);
    float nm = fmaxf(m, ee);
    float f = (m > -FLT_MAX) ? __expf(m - nm) : 0.f;
    float w = __expf(ee - nm);
    s = s * f + w; acc = acc * f + w * p; m = nm;
  }
  if constexpr (WPD == 1) {
    float r = acc / (s + 1e-16f);
    size_t o = (size_t)d * 64 + lane;
    if constexpr (EPI == 0) {
      out[o] = r;
    } else {
      float v = out[o] + r + eb1[lane] + eb2[lane];
      out[o] = (v > 0.f) ? v : expm1f(v);
    }
  } else {
    __shared__ float sm[4][64], ss[4][64], sacc[4][64];
    sm[wid][lane] = m; ss[wid][lane] = s; sacc[wid][lane] = acc;
    __syncthreads();
    if (wid == 0) {
      float M = -INFINITY;
      #pragma unroll
      for (int w2 = 0; w2 < 4; ++w2) M = fmaxf(M, sm[w2][lane]);
      float S = 0.f, A = 0.f;
      #pragma unroll
      for (int w2 = 0; w2 < 4; ++w2) {
        float mw = sm[w2][lane];
        float f = (mw > -FLT_MAX) ? __expf(mw - M) : 0.f;
        S += ss[w2][lane] * f;
        A += sacc[w2][lane] * f;
      }
      float r = A / (S + 1e-16f);
      float v = r + eb1[lane];                     // EPI==2
      out[(size_t)d * 64 + lane] = (v > 0.f) ? v : expm1f(v);
    }
  }
}

// ---------------- layer-2 gather (heads=1, C=64), table-based ----------------
// EPI: 0 plain write; 3 add-old + eb1 + eb2 + LN -> lnout; 4 (WPD=4) eb1 + LN -> lnout
template <int WPD, int CHUNK, int SELFMASK, int EPI>
__global__ void gat2_kernel(const unsigned* __restrict__ rp, const int* __restrict__ srcs,
                            const float* __restrict__ hl, const float* __restrict__ hr,
                            const float* __restrict__ att, float* __restrict__ out,
                            const float* __restrict__ eb1, const float* __restrict__ eb2,
                            const float* __restrict__ lw, const float* __restrict__ lb,
                            float* __restrict__ lnout, int n_dst, int nloop) {
  int lane = threadIdx.x & 63, wid = threadIdx.x >> 6;
  int d = (WPD == 1) ? (blockIdx.x * 4 + wid) : blockIdx.x;
  if (d >= n_dst) return;
  float a = att[lane];
  float hrv = hr[(size_t)d * 64 + lane];
  float m = -INFINITY, s = 0.f, acc = 0.f;
  unsigned beg = rp[d], end = rp[d + 1];
  for (unsigned i = beg + (WPD == 1 ? 0u : (unsigned)(wid * CHUNK)); i < end;
       i += WPD * CHUNK) {
    float pl[CHUNK], e[CHUNK];
    bool val[CHUNK];
    #pragma unroll
    for (int j = 0; j < CHUNK; ++j) {
      unsigned idx = i + j;
      int sv = (idx < end) ? srcs[idx] : 0;
      val[j] = (idx < end) && (!SELFMASK || sv != d);
      pl[j] = hl[(size_t)sv * 64 + lane];
    }
    #pragma unroll
    for (int j = 0; j < CHUNK; ++j) {
      float v = pl[j] + hrv;
      v = (v >= 0.f) ? v : 0.2f * v;
      float ee = v * a;
      #pragma unroll
      for (int off = 32; off > 0; off >>= 1) ee += __shfl_xor(ee, off, 64);
      e[j] = val[j] ? ee : -INFINITY;
    }
    float cmax = e[0];
    #pragma unroll
    for (int j = 1; j < CHUNK; ++j) cmax = fmaxf(cmax, e[j]);
    float nm = fmaxf(m, cmax);
    float f = (m > -FLT_MAX) ? __expf(m - nm) : 0.f;
    float ssum = 0.f, asum = 0.f;
    #pragma unroll
    for (int j = 0; j < CHUNK; ++j) {
      float w = (e[j] > -FLT_MAX) ? __expf(e[j] - nm) : 0.f;
      ssum += w;
      asum = fmaf(w, pl[j], asum);
    }
    s = s * f + ssum;
    acc = acc * f + asum;
    m = nm;
  }
  if ((WPD == 1 || wid == 0) && d < nloop) {       // self-loop (hl row d)
    float p = hl[(size_t)d * 64 + lane];
    float v = p + hrv; v = (v >= 0.f) ? v : 0.2f * v;
    float ee = v * a;
    #pragma unroll
    for (int off = 32; off > 0; off >>= 1) ee += __shfl_xor(ee, off, 64);
    float nm = fmaxf(m, ee);
    float f = (m > -FLT_MAX) ? __expf(m - nm) : 0.f;
    float w = __expf(ee - nm);
    s = s * f + w; acc = acc * f + w * p; m = nm;
  }
  if constexpr (WPD == 1) {
    float r = acc / (s + 1e-16f);
    size_t o = (size_t)d * 64 + lane;
    if constexpr (EPI == 0) {
      out[o] = r;
    } else {
      float v = out[o] + r + eb1[lane] + eb2[lane];
      lnout[o] = ln_row(v, lane, lw, lb);
    }
  } else {
    __shared__ float sm[4][64], ss[4][64], sacc[4][64];
    sm[wid][lane] = m; ss[wid][lane] = s; sacc[wid][lane] = acc;
    __syncthreads();
    if (wid == 0) {
      float M = -INFINITY;
      #pragma unroll
      for (int w2 = 0; w2 < 4; ++w2) M = fmaxf(M, sm[w2][lane]);
      float S = 0.f, A = 0.f;
      #pragma unroll
      for (int w2 = 0; w2 < 4; ++w2) {
        float mw = sm[w2][lane];
        float f = (mw > -FLT_MAX) ? __expf(mw - M) : 0.f;
        S += ss[w2][lane] * f;
        A += sacc[w2][lane] * f;
      }
      float r = A / (S + 1e-16f);
      float v = r + eb1[lane];                     // EPI==4
      lnout[(size_t)d * 64 + lane] = ln_row(v, lane, lw, lb);
    }
  }
}

// ---------------- fused dual projection (x-tile + weights in LDS, no spills) ----------------
__global__ __launch_bounds__(256, 2)
void proj2_kernel(const float* __restrict__ x,
                  const float* __restrict__ W0, const float* __restrict__ b0,
                  const float* __restrict__ W1, const float* __restrict__ b1,
                  float* __restrict__ out0, float* __restrict__ out1, int n) {
  __shared__ float w0s[4096], w1s[4096], xtile[2048];   // 40 KB
  int t = threadIdx.x;
  for (int i = t; i < 4096; i += 256) { w0s[i] = W0[i]; w1s[i] = W1[i]; }
  int base = blockIdx.x * 32;
  for (int i = t; i < 2048; i += 256) {
    int row = base + (i >> 6);
    int rc = (row < n) ? row : (n - 1);
    xtile[i] = x[(size_t)rc * 64 + (i & 63)];
  }
  __syncthreads();
  int lane = t & 63, wid = t >> 6;
  int wr = wid * 8;
  float acc0[8], acc1[8];
  #pragma unroll
  for (int r = 0; r < 8; ++r) { acc0[r] = 0.f; acc1[r] = 0.f; }
  for (int kq = 0; kq < 16; ++kq) {
    int k = kq * 4;
    float w00 = w0s[(k + 0) * 64 + lane];
    float w01 = w0s[(k + 1) * 64 + lane];
    float w02 = w0s[(k + 2) * 64 + lane];
    float w03 = w0s[(k + 3) * 64 + lane];
    float w10 = w1s[(k + 0) * 64 + lane];
    float w11 = w1s[(k + 1) * 64 + lane];
    float w12 = w1s[(k + 2) * 64 + lane];
    float w13 = w1s[(k + 3) * 64 + lane];
    #pragma unroll
    for (int r = 0; r < 8; ++r) {
      float4 xv = *(const float4*)&xtile[(wr + r) * 64 + k];
      acc0[r] = fmaf(xv.x, w00, acc0[r]);
      acc0[r] = fmaf(xv.y, w01, acc0[r]);
      acc0[r] = fmaf(xv.z, w02, acc0[r]);
      acc0[r] = fmaf(xv.w, w03, acc0[r]);
      acc1[r] = fmaf(xv.x, w10, acc1[r]);
      acc1[r] = fmaf(xv.y, w11, acc1[r]);
      acc1[r] = fmaf(xv.z, w12, acc1[r]);
      acc1[r] = fmaf(xv.w, w13, acc1[r]);
    }
  }
  float b0v = b0[lane], b1v = b1[lane];
  #pragma unroll
  for (int r = 0; r < 8; ++r) {
    int row = base + wr + r;
    if (row < n) {
      out0[(size_t)row * 64 + lane] = acc0[r] + b0v;
      out1[(size_t)row * 64 + lane] = acc1[r] + b1v;
    }
  }
}

extern "C" void kernel_launch(void* const* d_in, const int* in_sizes, int n_in,
                              void* d_out, int out_size, void* d_ws, size_t ws_size,
                              hipStream_t stream) {
  const float* x_veh = (const float*)d_in[0];
  const float* x_rsu = (const float*)d_in[1];
  const int* ei_v2v = (const int*)d_in[2];
  const int* ei_v2i = (const int*)d_in[3];
  const int* ei_i2v = (const int*)d_in[4];
  const float* P[36];
  for (int i = 0; i < 36; ++i) P[i] = (const float*)d_in[5 + i];
  // blocks of 6 (Wl, bl, Wr, br, att, b):
  // p1v P[0..5], p1i P[6..11], p1r P[12..17], p2v P[18..23], p2i P[24..29], p2r P[30..35]
  const float* lnv_w = (const float*)d_in[41];
  const float* lnv_b = (const float*)d_in[42];
  const float* lnr_w = (const float*)d_in[43];
  const float* lnr_b = (const float*)d_in[44];

  float* ws = (float*)d_ws;
  float* P0    = ws;
  float* P1    = P0 + 3200000;
  float* ACCV  = P1 + 3200000;         // h_veh
  float* ACC2V = ACCV + 3200000;
  float* S0    = ACC2V + 3200000;      // 32000
  float* S1    = S0 + 32000;
  float* ACCR  = S1 + 32000;           // h_rsu
  unsigned* cnt_all    = (unsigned*)(ACCR + 32000);    // CNT_LEN
  unsigned* rp_all     = cnt_all + CNT_LEN;            // RP_LEN
  unsigned* cursor_all = rp_all + RP_LEN;              // RP_LEN
  unsigned* tsum       = cursor_all + RP_LEN;          // 128
  unsigned* tbase      = tsum + 128;                   // 128
  int* src_all         = (int*)(tbase + 128);          // 600000
  // total ~55.2 MB

  const unsigned* rp_vv = rp_all + RB_VV;
  const unsigned* rp_vi = rp_all + RB_VI;
  const unsigned* rp_iv = rp_all + RB_IV;
  const int* src_vv = src_all;
  const int* src_vi = src_all + EVV;
  const int* src_iv = src_all + EVV + EVI;

  auto gsz = [](int n) { return (n + 255) / 256; };
  auto gsz4 = [](int n) { return (n + 3) / 4; };
  auto gszr = [](int n) { return (n + 31) / 32; };

  // ---- CSR build ----
  hipMemsetAsync(cnt_all, 0, (size_t)CNT_LEN * 4, stream);
  hist_all_kernel<<<gsz(EVV + EVI + EIV), 256, 0, stream>>>(
      ei_v2v, ei_v2v + EVV, ei_v2i + EVI, ei_i2v + EIV, cnt_all);
  tilesum_kernel<<<T_TOT, 256, 0, stream>>>(cnt_all, tsum);
  tilescan_kernel<<<1, 128, 0, stream>>>(tsum, tbase, rp_all);
  scanwrite_kernel<<<T_TOT, 256, 0, stream>>>(cnt_all, tbase, rp_all, cursor_all);
  fill_all_kernel<<<gsz(EVV + EVI + EIV), 256, 0, stream>>>(
      ei_v2v, ei_v2v + EVV, ei_v2i, ei_v2i + EVI, ei_i2v, ei_i2v + EIV, cursor_all, src_all);

  // ---- layer 1 (heads=2, C=32; inline projections, fused elu) ----
  gat1_kernel<1, 8, 6, 6, 0><<<gsz4(NV), 256, 0, stream>>>(
      rp_vv, src_vv, x_veh, x_veh, P[0], P[1], P[2], P[3], P[4], ACCV,
      nullptr, nullptr, NV, NV);
  gat1_kernel<1, 4, 1, 6, 1><<<gsz4(NV), 256, 0, stream>>>(
      rp_iv, src_iv, x_rsu, x_veh, P[12], P[13], P[14], P[15], P[16], ACCV,
      P[5], P[17], NV, 0);                                   // + elu -> h_veh
  gat1_kernel<4, 8, 6, 1, 2><<<NR, 256, 0, stream>>>(
      rp_vi, src_vi, x_veh, x_rsu, P[6], P[7], P[8], P[9], P[10], ACCR,
      P[11], nullptr, NR, 0);                                // + elu -> h_rsu

  // ---- layer 2 (heads=1, C=64; fused LN) ----
  proj2_kernel<<<gszr(NV), 256, 0, stream>>>(ACCV, P[18], P[19], P[20], P[21], P0, P1, NV);
  proj2_kernel<<<gszr(NR), 256, 0, stream>>>(ACCR, P[30], P[31], P[26], P[27], S0, S1, NR);
  gat2_kernel<1, 8, 0, 0><<<gsz4(NV), 256, 0, stream>>>(
      rp_vv, src_vv, P0, P1, P[22], ACC2V,
      nullptr, nullptr, nullptr, nullptr, nullptr, NV, NV);
  proj2_kernel<<<gszr(NV), 256, 0, stream>>>(ACCV, P[32], P[33], P[24], P[25], P1, P0, NV);
  gat2_kernel<1, 4, 1, 3><<<gsz4(NV), 256, 0, stream>>>(
      rp_iv, src_iv, S0, P1, P[34], ACC2V,
      P[23], P[35], lnv_w, lnv_b, (float*)d_out, NV, NR);    // + LN -> out veh
  gat2_kernel<4, 8, 1, 4><<<NR, 256, 0, stream>>>(
      rp_vi, src_vi, P0, S1, P[28], nullptr,
      P[29], nullptr, lnr_w, lnr_b, (float*)d_out + (size_t)NV * 64, NR, NR); // + LN -> out rsu
}